// Round 5
// baseline (5164.352 us; speedup 1.0000x reference)
//
#include <hip/hip_runtime.h>

#define RNUM 256
#define NB 64
#define KSEL 8
#define SNUM 256
#define HDIM 128
#define FEAT 32
#define EMB 16
#define NAPP 100
#define CINDIM 52
#define STEPF 0.5f
#define VIS_T 0.01f
#define TERM_T 0.99f
#define T_EPS 1e-4f

__device__ __forceinline__ float bf2f(unsigned short u) {
    unsigned int x = ((unsigned int)u) << 16;
    return __uint_as_float(x);
}
__device__ __forceinline__ unsigned short f2bf(float f) {
    unsigned int u = __float_as_uint(f);
    unsigned int r = (u + 0x7fffu + ((u >> 16) & 1u)) >> 16;
    return (unsigned short)r;
}

// Inverse-distance blend weight for (sample s, slot kk). Used for BOTH twL
// and the accumulators so the normalization is consistent by construction.
__device__ __forceinline__ float wv_at(int s, int kk, float nearr,
                                       float ox, float oy, float oz,
                                       float dx, float dy, float dz,
                                       const float* cselL, const int* selL,
                                       const float* wsumL)
{
    if (selL[kk] < 0) return 0.f;
    float ts = nearr + STEPF * (float)s;
    float px = ox + ts*dx, py = oy + ts*dy, pz = oz + ts*dz;
    float ex = px - cselL[kk*3], ey = py - cselL[kk*3+1], ez = pz - cselL[kk*3+2];
    float inv = 1.f / (sqrtf(ex*ex + ey*ey + ez*ez) + 1e-6f);
    float ws = wsumL[s];
    float w = (ws > 0.f) ? inv / fmaxf(ws, 1e-12f) : 0.f;
    return (w >= VIS_T) ? w : 0.f;
}

// One workgroup per ray. FLOAT32 output (reference computes f32 from f32 inputs).
__global__ __launch_bounds__(256) void fused_kernel(
    const float* __restrict__ ro, const float* __restrict__ rd,
    const float* __restrict__ bc, const float* __restrict__ br,
    const int* __restrict__ aid, const float* __restrict__ expo,
    const float* __restrict__ nearp, const float* __restrict__ farp,
    const float* __restrict__ W1, const float* __restrict__ b1,
    const float* __restrict__ W2, const float* __restrict__ b2,
    const float* __restrict__ Wd, const float* __restrict__ bd,
    const float* __restrict__ Wf, const float* __restrict__ Wc1,
    const float* __restrict__ bc1, const float* __restrict__ Wc2,
    const float* __restrict__ bc2, const float* __restrict__ app_emb,
    float* __restrict__ out)
{
    const int r = blockIdx.x;
    const int t = threadIdx.x;

    __shared__ float distL[NB];
    __shared__ int   selL[KSEL];
    __shared__ float cselL[KSEL*3];
    __shared__ float wsumL[SNUM];
    __shared__ float twL[SNUM];
    __shared__ float tdacc[SNUM];
    __shared__ float cacc[SNUM*3];                 // [ch][s]
    __shared__ unsigned short w2L[HDIM*HDIM];      // 32 KB bf16 [i][o]
    __shared__ unsigned short wfL[HDIM*FEAT];      // 8 KB bf16 [i][f]
    __shared__ unsigned short wc1L[CINDIM*64];     // 6.5 KB bf16 [c][e]
    __shared__ float w1L[3*HDIM];
    __shared__ float b1L[HDIM], b2L[HDIM], wdL[HDIM];
    __shared__ float bc1L[64], wc2L[192], bc2L[3], bdL, embL[EMB];
    __shared__ float h1buf[2*HDIM];                // [sp][i]
    __shared__ float h2buf[2*HDIM];                // [sp][o]
    __shared__ float hcbuf[2*64];                  // [sp][e]
    __shared__ float cinL[2*CINDIM];               // [sp][c]

    const float ox = ro[r*3], oy = ro[r*3+1], oz = ro[r*3+2];
    const float dx = rd[r*3], dy = rd[r*3+1], dz = rd[r*3+2];
    const float nearr = nearp[r];
    const float expv  = expo[r];
    const int   aidr  = aid[r];

    // ---- phase 0: ray-sphere selection ----
    if (t < NB) {
        const int nb = t;
        float a = dx*dx + dy*dy + dz*dz;
        float cx = bc[nb*3], cy = bc[nb*3+1], cz = bc[nb*3+2];
        float rad = br[nb];
        float ocx = ox-cx, ocy = oy-cy, ocz = oz-cz;
        float bq = 2.f*(ocx*dx + ocy*dy + ocz*dz);
        float cq = ocx*ocx + ocy*ocy + ocz*ocz - rad*rad;
        float disc = bq*bq - 4.f*a*cq;
        // ref quirk: sq = sqrt(where(disc>0, disc, 1.0)); sq = where(disc>=0, sq, 0)
        float sq = disc > 0.f ? sqrtf(disc) : (disc >= 0.f ? 1.f : 0.f);
        float t1 = (-bq - sq) / (2.f*a);
        float t2 = (-bq + sq) / (2.f*a);
        float th = t1 > 0.f ? t1 : t2;
        bool valid = (disc >= 0.f) && (th > 0.f);
        float hx = ox + th*dx - cx, hy = oy + th*dy - cy, hz = oz + th*dz - cz;
        distL[nb] = valid ? sqrtf(hx*hx + hy*hy + hz*hz) : INFINITY;
    }
    __syncthreads();
    if (t == 0) {
        for (int kk = 0; kk < KSEL; kk++) {
            float bd2 = INFINITY; int bi = -1;
            for (int j = 0; j < NB; j++) { if (distL[j] < bd2) { bd2 = distL[j]; bi = j; } }
            selL[kk] = bi;                    // -1 => invalid slot
            if (bi >= 0) distL[bi] = INFINITY;
        }
    }
    __syncthreads();
    if (t < KSEL*3) {
        int kk = t/3, j = t%3;
        int b = selL[kk];
        cselL[kk*3+j] = (b >= 0) ? bc[b*3+j] : 0.f;
    }
    __syncthreads();

    // ---- phase 0.5: per-sample wsum, tw; zero accumulators ----
    {
        const int s = t;
        float ts = nearr + STEPF*(float)s;
        float px = ox + ts*dx, py = oy + ts*dy, pz = oz + ts*dz;
        float wsum = 0.f;
        #pragma unroll
        for (int k2 = 0; k2 < KSEL; k2++) {
            if (selL[k2] >= 0) {
                float ex = px - cselL[k2*3], ey = py - cselL[k2*3+1], ez = pz - cselL[k2*3+2];
                wsum += 1.f / (sqrtf(ex*ex + ey*ey + ez*ez) + 1e-6f);
            }
        }
        wsumL[s] = wsum;
        float tw = 0.f;
        #pragma unroll
        for (int k2 = 0; k2 < KSEL; k2++)
            tw += wv_at(s, k2, nearr, ox,oy,oz, dx,dy,dz, cselL, selL, wsumL);
        twL[s] = tw;
        tdacc[s] = 0.f;
        cacc[s] = 0.f; cacc[s+SNUM] = 0.f; cacc[s+2*SNUM] = 0.f;
    }
    __syncthreads();

    const int sp = t >> 7;     // 0/1: which of the 2 samples this thread serves
    const int o  = t & 127;

    // ---- k-loop over selected blocks ----
    for (int kk = 0; kk < KSEL; kk++) {
        const int b = selL[kk];               // uniform
        if (b < 0) continue;

        { // stage weights (bf16 for the big three, f32 for the rest)
            const float* w2g = W2 + (size_t)b*HDIM*HDIM;
            for (int i = t; i < HDIM*HDIM; i += 256) w2L[i] = f2bf(w2g[i]);
            const float* wfg = Wf + (size_t)b*HDIM*FEAT;
            for (int i = t; i < HDIM*FEAT; i += 256) wfL[i] = f2bf(wfg[i]);
            const float* wc1g = Wc1 + (size_t)b*CINDIM*64;
            for (int i = t; i < CINDIM*64; i += 256) wc1L[i] = f2bf(wc1g[i]);
            const float* w1g = W1 + (size_t)b*3*HDIM;
            for (int i = t; i < 3*HDIM; i += 256) w1L[i] = w1g[i];
            if (t < HDIM) { b1L[t] = b1[b*HDIM+t]; b2L[t] = b2[b*HDIM+t]; wdL[t] = Wd[b*HDIM+t]; }
            if (t < 64)  bc1L[t] = bc1[b*64+t];
            if (t < 192) wc2L[t] = Wc2[b*192+t];
            if (t < 3)   bc2L[t] = bc2[b*3+t];
            if (t == 0)  bdL = bd[b];
            if (t < EMB) embL[t] = app_emb[((size_t)b*NAPP + aidr)*EMB + t];
        }
        __syncthreads();

        for (int s0 = 0; s0 < SNUM; s0 += 2) {
            const int s = s0 + sp;
            // h1 = relu(pos.W1 + b1)
            {
                float ts = nearr + STEPF*(float)s;
                float px = ox + ts*dx, py = oy + ts*dy, pz = oz + ts*dz;
                float v = fmaf(px, w1L[o], fmaf(py, w1L[HDIM+o], fmaf(pz, w1L[2*HDIM+o], b1L[o])));
                h1buf[sp*HDIM+o] = fmaxf(v, 0.f);
            }
            __syncthreads();
            // h2 = relu(h1.W2 + b2) — full 128-dot per thread
            {
                float acc2 = 0.f;
                #pragma unroll 8
                for (int i = 0; i < HDIM; i++)
                    acc2 = fmaf(h1buf[sp*HDIM+i], bf2f(w2L[i*HDIM+o]), acc2);
                h2buf[sp*HDIM+o] = fmaxf(acc2 + b2L[o], 0.f);
            }
            __syncthreads();
            // feat (t<64) | sigma (t in [64,66)) | cin extras (t in [128,168))
            if (t < 64) {
                int sp2 = t>>5, f = t&31;
                float p = 0.f;
                #pragma unroll 8
                for (int i = 0; i < HDIM; i++)
                    p = fmaf(h2buf[sp2*HDIM+i], bf2f(wfL[i*FEAT+f]), p);
                cinL[sp2*CINDIM+f] = p;
            } else if (t < 66) {
                int sp2 = t - 64;
                float p = 0.f;
                #pragma unroll 8
                for (int i = 0; i < HDIM; i++)
                    p = fmaf(h2buf[sp2*HDIM+i], wdL[i], p);
                float x = p + bdL;
                float sg = log1pf(expf(-fabsf(x))) + fmaxf(x, 0.f);
                tdacc[s0+sp2] += sg * wv_at(s0+sp2, kk, nearr, ox,oy,oz, dx,dy,dz, cselL, selL, wsumL);
            } else if (t >= 128 && t < 168) {
                int idx = t - 128;
                int sp2 = idx/20, c2 = idx%20;
                float v;
                if (c2 < 3)       v = (c2==0 ? dx : (c2==1 ? dy : dz));
                else if (c2 < 19) v = embL[c2-3];
                else              v = expv;
                cinL[sp2*CINDIM+32+c2] = v;
            }
            __syncthreads();
            // hc = relu(cin.Wc1 + bc1)
            if (t < 128) {
                int sp2 = t>>6, e = t&63;
                float p = bc1L[e];
                #pragma unroll 4
                for (int c = 0; c < CINDIM; c++)
                    p = fmaf(cinL[sp2*CINDIM+c], bf2f(wc1L[c*64+e]), p);
                hcbuf[sp2*64+e] = fmaxf(p, 0.f);
            }
            __syncthreads();
            // color = sigmoid(hc.Wc2 + bc2); accumulate color*wv
            if (t < 6) {
                int sp2 = t/3, ch = t%3;
                float p = 0.f;
                #pragma unroll 8
                for (int e = 0; e < 64; e++)
                    p = fmaf(hcbuf[sp2*64+e], wc2L[e*3+ch], p);
                float x = p + bc2L[ch];
                float cv = 1.f/(1.f+expf(-x));
                cacc[ch*SNUM + s0+sp2] += cv * wv_at(s0+sp2, kk, nearr, ox,oy,oz, dx,dy,dz, cselL, selL, wsumL);
            }
            __syncthreads();
        }
        __syncthreads();
    }

    // ---- sequential compositing (alpha & color-norm computed inline) ----
    if (t == 0) {
        const float farr = farp[r];
        float T = 1.f, acc = 0.f, rgb0=0.f, rgb1=0.f, rgb2=0.f, dep=0.f;
        for (int s = 0; s < SNUM; s++) {
            float ts = nearr + STEPF*(float)s;
            bool alive = (ts < farr) && (T > T_EPS) && (acc <= TERM_T);
            float a = fminf(fmaxf(1.f - expf(-tdacc[s]*STEPF), 0.f), 1.f);
            float tw = twL[s];
            float c0 = cacc[s], c1 = cacc[s+SNUM], c2 = cacc[s+2*SNUM];
            if (tw > 0.f) {
                float dv = fmaxf(tw, 1e-12f);
                c0 /= dv; c1 /= dv; c2 /= dv;
            }
            float wgt = alive ? T*a : 0.f;
            rgb0 += wgt*c0; rgb1 += wgt*c1; rgb2 += wgt*c2;
            acc += wgt;
            dep += wgt*ts;
            T *= alive ? (1.f - a) : 1.f;
        }
        float depth = dep / fmaxf(acc, 1e-6f);
        out[r*3+0] = rgb0;
        out[r*3+1] = rgb1;
        out[r*3+2] = rgb2;
        out[RNUM*3 + r]        = depth;
        out[RNUM*3 + RNUM + r] = acc;
    }
}

extern "C" void kernel_launch(void* const* d_in, const int* in_sizes, int n_in,
                              void* d_out, int out_size, void* d_ws, size_t ws_size,
                              hipStream_t stream) {
    const float* ro    = (const float*)d_in[0];
    const float* rd    = (const float*)d_in[1];
    const float* bc    = (const float*)d_in[2];
    const float* br    = (const float*)d_in[3];
    const int*   aidp  = (const int*)d_in[4];
    const float* expo  = (const float*)d_in[5];
    const float* nearp = (const float*)d_in[6];
    const float* farp  = (const float*)d_in[7];
    const float* W1    = (const float*)d_in[8];
    const float* b1    = (const float*)d_in[9];
    const float* W2    = (const float*)d_in[10];
    const float* b2    = (const float*)d_in[11];
    const float* Wd    = (const float*)d_in[12];
    const float* bd    = (const float*)d_in[13];
    const float* Wf    = (const float*)d_in[14];
    const float* Wc1   = (const float*)d_in[15];
    const float* bc1   = (const float*)d_in[16];
    const float* Wc2   = (const float*)d_in[17];
    const float* bc2   = (const float*)d_in[18];
    const float* appe  = (const float*)d_in[19];
    float* outp = (float*)d_out;

    fused_kernel<<<RNUM, 256, 0, stream>>>(ro, rd, bc, br, aidp, expo, nearp, farp,
                                           W1, b1, W2, b2, Wd, bd, Wf, Wc1, bc1, Wc2, bc2,
                                           appe, outp);
}

// Round 6
// 299.393 us; speedup vs baseline: 17.2494x; 17.2494x over previous
//
#include <hip/hip_runtime.h>

#define RNUM 256
#define NB 64
#define KSEL 8
#define SNUM 256
#define HDIM 128
#define FEAT 32
#define EMB 16
#define NAPP 100
#define CINDIM 52
#define STEPF 0.5f
#define VIS_T 0.01f
#define TERM_T 0.99f
#define T_EPS 1e-4f

// packed-weight sizes (ushort units) per block
#define W2P_SZ   16384      // 8 ntiles * 4 ksteps * 64 lanes * 8
#define WFDP_SZ  6144       // 3 ntiles * 4 ksteps * 64 * 8   (N=48: feat32 | Wd | 0)
#define WC1P_SZ  4096       // 4 ntiles * 2 ksteps * 64 * 8   (K=64: 52 | 0-pad)
#define BLK_SZ   (W2P_SZ + WFDP_SZ + WC1P_SZ)   // 26624 ushorts = 53248 B

typedef __attribute__((ext_vector_type(8))) short bh8;
typedef __attribute__((ext_vector_type(4))) float f32x4;

__device__ __forceinline__ unsigned short f2bf(float f) {
    unsigned int u = __float_as_uint(f);
    unsigned int r = (u + 0x7fffu + ((u >> 16) & 1u)) >> 16;
    return (unsigned short)r;
}

// ---------------- prep: pack weights into MFMA B-fragment layout ----------------
// B-frag for mfma_f32_16x16x32_bf16: lane l holds B[k = 8*(l>>4)+b][n = l&15], b=0..7.
// slot index = unit*64 + l, unit enumerates (ntile, kstep).
__global__ __launch_bounds__(256) void pack_kernel(
    const float* __restrict__ W2, const float* __restrict__ Wf,
    const float* __restrict__ Wd, const float* __restrict__ Wc1,
    unsigned short* __restrict__ wsu)
{
    const int blk = blockIdx.x, t = threadIdx.x;
    unsigned short* w2p  = wsu + (size_t)blk * BLK_SZ;
    unsigned short* wfdp = w2p + W2P_SZ;
    unsigned short* wc1p = w2p + W2P_SZ + WFDP_SZ;
    const float* W2b  = W2  + (size_t)blk * HDIM * HDIM;
    const float* Wfb  = Wf  + (size_t)blk * HDIM * FEAT;
    const float* Wdb  = Wd  + (size_t)blk * HDIM;
    const float* Wc1b = Wc1 + (size_t)blk * CINDIM * 64;

    for (int slot = t; slot < 8*4*64; slot += 256) {         // W2: N=128, K=128
        int unit = slot >> 6, l = slot & 63;
        int n0 = unit >> 2, k0 = unit & 3, q = l >> 4, lr = l & 15;
        bh8 v;
        #pragma unroll
        for (int bb = 0; bb < 8; bb++) {
            int row = k0*32 + 8*q + bb;
            v[bb] = (short)f2bf(W2b[row*HDIM + n0*16 + lr]);
        }
        ((bh8*)w2p)[slot] = v;
    }
    for (int slot = t; slot < 3*4*64; slot += 256) {         // [Wf | Wd | 0]: N=48, K=128
        int unit = slot >> 6, l = slot & 63;
        int n0 = unit >> 2, k0 = unit & 3, q = l >> 4, lr = l & 15;
        int gcol = n0*16 + lr;
        bh8 v;
        #pragma unroll
        for (int bb = 0; bb < 8; bb++) {
            int row = k0*32 + 8*q + bb;
            float val = (gcol < FEAT) ? Wfb[row*FEAT + gcol]
                       : ((gcol == FEAT) ? Wdb[row] : 0.f);
            v[bb] = (short)f2bf(val);
        }
        ((bh8*)wfdp)[slot] = v;
    }
    for (int slot = t; slot < 4*2*64; slot += 256) {         // Wc1: N=64, K=64 (52 used)
        int unit = slot >> 6, l = slot & 63;
        int n0 = unit >> 1, k0 = unit & 1, q = l >> 4, lr = l & 15;
        bh8 v;
        #pragma unroll
        for (int bb = 0; bb < 8; bb++) {
            int row = k0*32 + 8*q + bb;
            float val = (row < CINDIM) ? Wc1b[row*64 + n0*16 + lr] : 0.f;
            v[bb] = (short)f2bf(val);
        }
        ((bh8*)wc1p)[slot] = v;
    }
}

__device__ __forceinline__ float wv_at(int s, int kk, float nearr,
                                       float ox, float oy, float oz,
                                       float dx, float dy, float dz,
                                       const float* cselL, const int* selL,
                                       const float* wsumL)
{
    if (selL[kk] < 0) return 0.f;
    float ts = nearr + STEPF * (float)s;
    float px = ox + ts*dx, py = oy + ts*dy, pz = oz + ts*dz;
    float ex = px - cselL[kk*3], ey = py - cselL[kk*3+1], ez = pz - cselL[kk*3+2];
    float inv = 1.f / (sqrtf(ex*ex + ey*ey + ez*ez) + 1e-6f);
    float ws = wsumL[s];
    float w = (ws > 0.f) ? inv / fmaxf(ws, 1e-12f) : 0.f;
    return (w >= VIS_T) ? w : 0.f;
}

// ---------------- fused: one WG (512 thr, 8 waves) per ray; MFMA MLP ----------------
__global__ __launch_bounds__(512, 2) void fused_kernel(
    const float* __restrict__ ro, const float* __restrict__ rd,
    const float* __restrict__ bc, const float* __restrict__ br,
    const int* __restrict__ aid, const float* __restrict__ expo,
    const float* __restrict__ nearp, const float* __restrict__ farp,
    const float* __restrict__ W1, const float* __restrict__ b1,
    const float* __restrict__ b2, const float* __restrict__ bd,
    const float* __restrict__ bc1, const float* __restrict__ Wc2,
    const float* __restrict__ bc2, const float* __restrict__ app_emb,
    const unsigned short* __restrict__ wsu,
    float* __restrict__ out)
{
    const int r = blockIdx.x, t = threadIdx.x;
    const int wave = t >> 6, l = t & 63, lq = l >> 4, lr = l & 15;

    __shared__ float distL[NB];
    __shared__ int   selL[KSEL];
    __shared__ float cselL[KSEL*3];
    __shared__ float wsumL[SNUM], twL[SNUM], tdacc[SNUM], cacc[3*SNUM];
    __shared__ float w1p[HDIM*4];                 // (w1x,w1y,w1z,b1) per i
    __shared__ float b2L[HDIM], bc1L[64], wc2L[192], bc2L[3], embL[EMB];
    __shared__ float bdL;
    __shared__ unsigned short H2L[8*32*HDIM];     // 64 KB, per-wave [32][128] bf16, swizzled
    __shared__ unsigned short CINL[8*32*64];      // 32 KB, per-wave [32][64] bf16, swizzled

    const float ox = ro[r*3], oy = ro[r*3+1], oz = ro[r*3+2];
    const float dx = rd[r*3], dy = rd[r*3+1], dz = rd[r*3+2];
    const float nearr = nearp[r];
    const float expv  = expo[r];
    const int   aidr  = aid[r];

    // ---- selection (proven R5 path) ----
    if (t < NB) {
        const int nb = t;
        float a = dx*dx + dy*dy + dz*dz;
        float cx = bc[nb*3], cy = bc[nb*3+1], cz = bc[nb*3+2];
        float rad = br[nb];
        float ocx = ox-cx, ocy = oy-cy, ocz = oz-cz;
        float bq = 2.f*(ocx*dx + ocy*dy + ocz*dz);
        float cq = ocx*ocx + ocy*ocy + ocz*ocz - rad*rad;
        float disc = bq*bq - 4.f*a*cq;
        float sq = disc > 0.f ? sqrtf(disc) : (disc >= 0.f ? 1.f : 0.f);
        float t1 = (-bq - sq) / (2.f*a);
        float t2 = (-bq + sq) / (2.f*a);
        float th = t1 > 0.f ? t1 : t2;
        bool valid = (disc >= 0.f) && (th > 0.f);
        float hx = ox + th*dx - cx, hy = oy + th*dy - cy, hz = oz + th*dz - cz;
        distL[nb] = valid ? sqrtf(hx*hx + hy*hy + hz*hz) : INFINITY;
    }
    __syncthreads();
    if (t == 0) {
        for (int kk = 0; kk < KSEL; kk++) {
            float bd2 = INFINITY; int bi = -1;
            for (int j = 0; j < NB; j++) { if (distL[j] < bd2) { bd2 = distL[j]; bi = j; } }
            selL[kk] = bi;
            if (bi >= 0) distL[bi] = INFINITY;
        }
    }
    __syncthreads();
    if (t < KSEL*3) {
        int kk = t/3, j = t%3;
        int b = selL[kk];
        cselL[kk*3+j] = (b >= 0) ? bc[b*3+j] : 0.f;
    }
    __syncthreads();

    // ---- wsum / tw / zero accumulators (proven R5 path) ----
    if (t < SNUM) {
        const int s = t;
        float ts = nearr + STEPF*(float)s;
        float px = ox + ts*dx, py = oy + ts*dy, pz = oz + ts*dz;
        float wsum = 0.f;
        #pragma unroll
        for (int k2 = 0; k2 < KSEL; k2++) {
            if (selL[k2] >= 0) {
                float ex = px - cselL[k2*3], ey = py - cselL[k2*3+1], ez = pz - cselL[k2*3+2];
                wsum += 1.f / (sqrtf(ex*ex + ey*ey + ez*ez) + 1e-6f);
            }
        }
        wsumL[s] = wsum;
        float tw = 0.f;
        #pragma unroll
        for (int k2 = 0; k2 < KSEL; k2++)
            tw += wv_at(s, k2, nearr, ox,oy,oz, dx,dy,dz, cselL, selL, wsumL);
        twL[s] = tw;
        tdacc[s] = 0.f;
        cacc[s] = 0.f; cacc[s+SNUM] = 0.f; cacc[s+2*SNUM] = 0.f;
    }
    __syncthreads();

    const f32x4 zero4 = {0.f, 0.f, 0.f, 0.f};

    // ---- k-loop over selected blocks ----
    for (int kk = 0; kk < KSEL; kk++) {
        const int b = selL[kk];               // uniform
        if (b < 0) continue;

        // stage small vectors
        if (t < HDIM) {
            const float* w1g = W1 + (size_t)b*3*HDIM;
            w1p[t*4+0] = w1g[t];
            w1p[t*4+1] = w1g[HDIM+t];
            w1p[t*4+2] = w1g[2*HDIM+t];
            w1p[t*4+3] = b1[b*HDIM+t];
            b2L[t] = b2[b*HDIM+t];
        } else if (t < 192) {
            bc1L[t-128] = bc1[b*64 + (t-128)];
        } else if (t < 384) {
            wc2L[t-192] = Wc2[b*192 + (t-192)];
        } else if (t < 400) {
            embL[t-384] = app_emb[((size_t)b*NAPP + aidr)*EMB + (t-384)];
        } else if (t == 400) {
            bdL = bd[b];
        } else if (t >= 404 && t < 407) {
            bc2L[t-404] = bc2[b*3 + (t-404)];
        }
        __syncthreads();

        // ---- A-fragments of H1 computed directly in registers ----
        // A-frag: lane holds A[row = l&15][k = 8*(l>>4)+b], rows = samples.
        float pxm[2], pym[2], pzm[2];
        #pragma unroll
        for (int mt = 0; mt < 2; mt++) {
            int s = wave*32 + mt*16 + lr;
            float ts = nearr + STEPF*(float)s;
            pxm[mt] = ox + ts*dx; pym[mt] = oy + ts*dy; pzm[mt] = oz + ts*dz;
        }
        bh8 afrag[2][4];
        #pragma unroll
        for (int mt = 0; mt < 2; mt++)
        #pragma unroll
        for (int k0 = 0; k0 < 4; k0++)
        #pragma unroll
        for (int bb = 0; bb < 8; bb++) {
            int i = k0*32 + 8*lq + bb;
            float4 w = ((const float4*)w1p)[i];
            float v = fmaf(pxm[mt], w.x, fmaf(pym[mt], w.y, fmaf(pzm[mt], w.z, w.w)));
            afrag[mt][k0][bb] = (short)f2bf(fmaxf(v, 0.f));
        }

        // ---- GEMM1: H2[32][128] = relu(H1 . W2 + b2) ----
        const unsigned short* w2p = wsu + (size_t)b*BLK_SZ;
        f32x4 acc1[2][8];
        #pragma unroll
        for (int mt = 0; mt < 2; mt++)
        #pragma unroll
        for (int nt = 0; nt < 8; nt++) acc1[mt][nt] = zero4;
        #pragma unroll
        for (int nt = 0; nt < 8; nt++) {
            bh8 bf0 = ((const bh8*)w2p)[(nt*4+0)*64 + l];
            bh8 bf1 = ((const bh8*)w2p)[(nt*4+1)*64 + l];
            bh8 bf2 = ((const bh8*)w2p)[(nt*4+2)*64 + l];
            bh8 bf3 = ((const bh8*)w2p)[(nt*4+3)*64 + l];
            #pragma unroll
            for (int mt = 0; mt < 2; mt++) {
                acc1[mt][nt] = __builtin_amdgcn_mfma_f32_16x16x32_bf16(afrag[mt][0], bf0, acc1[mt][nt], 0,0,0);
                acc1[mt][nt] = __builtin_amdgcn_mfma_f32_16x16x32_bf16(afrag[mt][1], bf1, acc1[mt][nt], 0,0,0);
                acc1[mt][nt] = __builtin_amdgcn_mfma_f32_16x16x32_bf16(afrag[mt][2], bf2, acc1[mt][nt], 0,0,0);
                acc1[mt][nt] = __builtin_amdgcn_mfma_f32_16x16x32_bf16(afrag[mt][3], bf3, acc1[mt][nt], 0,0,0);
            }
        }
        // epilogue: +b2, relu, write bf16 to swizzled LDS. C/D: col=l&15, row=(l>>4)*4+reg.
        #pragma unroll
        for (int mt = 0; mt < 2; mt++)
        #pragma unroll
        for (int nt = 0; nt < 8; nt++) {
            int col = nt*16 + lr;
            float bb2 = b2L[col];
            #pragma unroll
            for (int reg = 0; reg < 4; reg++) {
                int sl = mt*16 + lq*4 + reg;
                float v = fmaxf(acc1[mt][nt][reg] + bb2, 0.f);
                int g = (col >> 3) ^ (sl & 7);
                H2L[wave*4096 + sl*128 + (g<<3) + (col & 7)] = f2bf(v);
            }
        }
        __syncthreads();

        // ---- GEMM2: [feat(32) | sigma | pad] = H2 . [Wf|Wd|0] ----
        bh8 afr2[2][4];
        #pragma unroll
        for (int mt = 0; mt < 2; mt++)
        #pragma unroll
        for (int k0 = 0; k0 < 4; k0++) {
            int sl = mt*16 + lr;
            int g = (k0*4 + lq) ^ (sl & 7);
            afr2[mt][k0] = *(const bh8*)&H2L[wave*4096 + sl*128 + (g<<3)];
        }
        const unsigned short* wfdp = w2p + W2P_SZ;
        f32x4 acc2[2][3];
        #pragma unroll
        for (int mt = 0; mt < 2; mt++)
        #pragma unroll
        for (int nt = 0; nt < 3; nt++) acc2[mt][nt] = zero4;
        #pragma unroll
        for (int nt = 0; nt < 3; nt++) {
            bh8 bf0 = ((const bh8*)wfdp)[(nt*4+0)*64 + l];
            bh8 bf1 = ((const bh8*)wfdp)[(nt*4+1)*64 + l];
            bh8 bf2 = ((const bh8*)wfdp)[(nt*4+2)*64 + l];
            bh8 bf3 = ((const bh8*)wfdp)[(nt*4+3)*64 + l];
            #pragma unroll
            for (int mt = 0; mt < 2; mt++) {
                acc2[mt][nt] = __builtin_amdgcn_mfma_f32_16x16x32_bf16(afr2[mt][0], bf0, acc2[mt][nt], 0,0,0);
                acc2[mt][nt] = __builtin_amdgcn_mfma_f32_16x16x32_bf16(afr2[mt][1], bf1, acc2[mt][nt], 0,0,0);
                acc2[mt][nt] = __builtin_amdgcn_mfma_f32_16x16x32_bf16(afr2[mt][2], bf2, acc2[mt][nt], 0,0,0);
                acc2[mt][nt] = __builtin_amdgcn_mfma_f32_16x16x32_bf16(afr2[mt][3], bf3, acc2[mt][nt], 0,0,0);
            }
        }
        // sigma (column 32 = ntile 2, col 0): softplus, * wv, accumulate
        if (lr == 0) {
            #pragma unroll
            for (int mt = 0; mt < 2; mt++)
            #pragma unroll
            for (int reg = 0; reg < 4; reg++) {
                int sg = wave*32 + mt*16 + lq*4 + reg;
                float x = acc2[mt][2][reg] + bdL;
                float sgm = log1pf(expf(-fabsf(x))) + fmaxf(x, 0.f);
                tdacc[sg] += sgm * wv_at(sg, kk, nearr, ox,oy,oz, dx,dy,dz, cselL, selL, wsumL);
            }
        }
        // feat -> CIN LDS (cols 0..31)
        #pragma unroll
        for (int mt = 0; mt < 2; mt++)
        #pragma unroll
        for (int nt = 0; nt < 2; nt++) {
            int f = nt*16 + lr;
            #pragma unroll
            for (int reg = 0; reg < 4; reg++) {
                int sl = mt*16 + lq*4 + reg;
                int g = (f >> 3) ^ (sl & 7);
                CINL[wave*2048 + sl*64 + (g<<3) + (f & 7)] = f2bf(acc2[mt][nt][reg]);
            }
        }
        // CIN extras: cols 32..63 = [d(3), emb(16), exp(1), 0-pad]
        {
            int sl = l & 31, cg = l >> 5;
            #pragma unroll
            for (int j = 0; j < 16; j++) {
                int c = 32 + cg*16 + j;
                float v;
                if (c < 35)       v = (c==32 ? dx : (c==33 ? dy : dz));
                else if (c < 51)  v = embL[c-35];
                else if (c == 51) v = expv;
                else              v = 0.f;
                int g = (c >> 3) ^ (sl & 7);
                CINL[wave*2048 + sl*64 + (g<<3) + (c & 7)] = f2bf(v);
            }
        }
        __syncthreads();

        // ---- GEMM3: HC[32][64] = relu(CIN . Wc1 + bc1) ----
        bh8 afr3[2][2];
        #pragma unroll
        for (int mt = 0; mt < 2; mt++)
        #pragma unroll
        for (int k0 = 0; k0 < 2; k0++) {
            int sl = mt*16 + lr;
            int g = (k0*4 + lq) ^ (sl & 7);
            afr3[mt][k0] = *(const bh8*)&CINL[wave*2048 + sl*64 + (g<<3)];
        }
        const unsigned short* wc1p = w2p + W2P_SZ + WFDP_SZ;
        f32x4 acc3[2][4];
        #pragma unroll
        for (int mt = 0; mt < 2; mt++)
        #pragma unroll
        for (int nt = 0; nt < 4; nt++) acc3[mt][nt] = zero4;
        #pragma unroll
        for (int nt = 0; nt < 4; nt++) {
            bh8 bf0 = ((const bh8*)wc1p)[(nt*2+0)*64 + l];
            bh8 bf1 = ((const bh8*)wc1p)[(nt*2+1)*64 + l];
            #pragma unroll
            for (int mt = 0; mt < 2; mt++) {
                acc3[mt][nt] = __builtin_amdgcn_mfma_f32_16x16x32_bf16(afr3[mt][0], bf0, acc3[mt][nt], 0,0,0);
                acc3[mt][nt] = __builtin_amdgcn_mfma_f32_16x16x32_bf16(afr3[mt][1], bf1, acc3[mt][nt], 0,0,0);
            }
        }
        // color: hc=relu(acc3+bc1); p_ch = sum_e hc*wc2; 16-lane reduce; sigmoid; accumulate
        #pragma unroll
        for (int mt = 0; mt < 2; mt++)
        #pragma unroll
        for (int reg = 0; reg < 4; reg++) {
            float p0 = 0.f, p1 = 0.f, p2 = 0.f;
            #pragma unroll
            for (int nt = 0; nt < 4; nt++) {
                int e = nt*16 + lr;
                float hc = fmaxf(acc3[mt][nt][reg] + bc1L[e], 0.f);
                p0 = fmaf(hc, wc2L[e*3+0], p0);
                p1 = fmaf(hc, wc2L[e*3+1], p1);
                p2 = fmaf(hc, wc2L[e*3+2], p2);
            }
            #pragma unroll
            for (int m = 1; m < 16; m <<= 1) {
                p0 += __shfl_xor(p0, m);
                p1 += __shfl_xor(p1, m);
                p2 += __shfl_xor(p2, m);
            }
            if (lr == 0) {
                int sg = wave*32 + mt*16 + lq*4 + reg;
                float wvv = wv_at(sg, kk, nearr, ox,oy,oz, dx,dy,dz, cselL, selL, wsumL);
                cacc[0*SNUM+sg] += wvv / (1.f + expf(-(p0 + bc2L[0])));
                cacc[1*SNUM+sg] += wvv / (1.f + expf(-(p1 + bc2L[1])));
                cacc[2*SNUM+sg] += wvv / (1.f + expf(-(p2 + bc2L[2])));
            }
        }
        __syncthreads();
    }

    __syncthreads();

    // ---- sequential compositing (proven R5 path) ----
    if (t == 0) {
        const float farr = farp[r];
        float T = 1.f, acc = 0.f, rgb0=0.f, rgb1=0.f, rgb2=0.f, dep=0.f;
        for (int s = 0; s < SNUM; s++) {
            float ts = nearr + STEPF*(float)s;
            bool alive = (ts < farr) && (T > T_EPS) && (acc <= TERM_T);
            float a = fminf(fmaxf(1.f - expf(-tdacc[s]*STEPF), 0.f), 1.f);
            float tw = twL[s];
            float c0 = cacc[s], c1 = cacc[s+SNUM], c2 = cacc[s+2*SNUM];
            if (tw > 0.f) {
                float dv = fmaxf(tw, 1e-12f);
                c0 /= dv; c1 /= dv; c2 /= dv;
            }
            float wgt = alive ? T*a : 0.f;
            rgb0 += wgt*c0; rgb1 += wgt*c1; rgb2 += wgt*c2;
            acc += wgt;
            dep += wgt*ts;
            T *= alive ? (1.f - a) : 1.f;
        }
        float depth = dep / fmaxf(acc, 1e-6f);
        out[r*3+0] = rgb0;
        out[r*3+1] = rgb1;
        out[r*3+2] = rgb2;
        out[RNUM*3 + r]        = depth;
        out[RNUM*3 + RNUM + r] = acc;
    }
}

extern "C" void kernel_launch(void* const* d_in, const int* in_sizes, int n_in,
                              void* d_out, int out_size, void* d_ws, size_t ws_size,
                              hipStream_t stream) {
    const float* ro    = (const float*)d_in[0];
    const float* rd    = (const float*)d_in[1];
    const float* bc    = (const float*)d_in[2];
    const float* br    = (const float*)d_in[3];
    const int*   aidp  = (const int*)d_in[4];
    const float* expo  = (const float*)d_in[5];
    const float* nearp = (const float*)d_in[6];
    const float* farp  = (const float*)d_in[7];
    const float* W1    = (const float*)d_in[8];
    const float* b1    = (const float*)d_in[9];
    const float* W2    = (const float*)d_in[10];
    const float* b2    = (const float*)d_in[11];
    const float* Wd    = (const float*)d_in[12];
    const float* bd    = (const float*)d_in[13];
    const float* Wf    = (const float*)d_in[14];
    const float* Wc1   = (const float*)d_in[15];
    const float* bc1   = (const float*)d_in[16];
    const float* Wc2   = (const float*)d_in[17];
    const float* bc2   = (const float*)d_in[18];
    const float* appe  = (const float*)d_in[19];
    float* outp = (float*)d_out;
    unsigned short* wsu = (unsigned short*)d_ws;

    pack_kernel<<<NB, 256, 0, stream>>>(W2, Wf, Wd, Wc1, wsu);
    fused_kernel<<<RNUM, 512, 0, stream>>>(ro, rd, bc, br, aidp, expo, nearp, farp,
                                           W1, b1, b2, bd, bc1, Wc2, bc2, appe,
                                           wsu, outp);
}